// Round 8
// baseline (2783.495 us; speedup 1.0000x reference)
//
#include <hip/hip_runtime.h>
#include <stdint.h>

// FANeuron fused single-kernel producer/consumer:
//  - scan role (blockIdx < nscan): 1 chain/thread, 16-deep register prefetch,
//    sequential bit-exact recurrence; at every L_CHUNK boundary stores the
//    exact (ema, nr) seed and releases a per-chunk flag (agent scope).
//  - emit role: one thread per (chain, chunk); acquire-spins on its chunk's
//    flag, then replays the chunk bit-exactly writing va_trace + spikes.
//  All blocks are co-resident (2176 waves << capacity at VGPR<=128, LDS=0),
//  so spin-wait cannot deadlock. Emit keeps the chip busy (clocks + issue)
//  while the serial scan runs -> scan and emit overlap inside one dispatch.

#define L_CHUNK 256
#define SCAN_PF 16
#define K2_UNROLL 8

__global__ __launch_bounds__(256, 4)
void fa_fused_kernel(const float* __restrict__ x,
                     const float* __restrict__ vb,
                     const float* __restrict__ A,
                     const float* __restrict__ th,
                     const float* __restrict__ gain,
                     const float* __restrict__ tref,
                     float* __restrict__ emas,   // [nchunks][N]
                     int*   __restrict__ nrs,    // [nchunks][N]
                     int*   __restrict__ done,   // [nchunks]
                     float* __restrict__ out,
                     int B, int T, int F, int nchunks, int nscan) {
#pragma clang fp contract(off)
    const int N = B * F;
    const float alpha = 0.001f;                  // f32(0.05/50)

    if ((int)blockIdx.x < nscan) {
        // ---------------- scan role ----------------
        const int ci = blockIdx.x * 256 + threadIdx.x;   // = b*F + f
        const int f = ci % F;
        const int b = ci / F;
        const float vbf = vb[f], Af = A[f], thf = th[f], gf = gain[f];
        const int rs = (int)fmaxf(ceilf(tref[f] / 0.05f), 1.0f);
        const float* xp = x + (size_t)b * T * F + f;

        bool fast = __all((gf == 1.0f) && (Af == 1.0f) && (vbf == 0.0f));

        float cur[SCAN_PF], nxt[SCAN_PF];
#pragma unroll
        for (int j = 0; j < SCAN_PF; ++j) cur[j] = xp[(size_t)j * F];

        // bit-exact t==0 seeding: ema = xt(0); step t=0 then yields
        // fl(xt + alpha*0) = xt, so the loop needs no special case.
        float ema = fast ? cur[0] : (cur[0] * gf);
        int nr = 0;                                    // absolute next-ready step

        for (int t0 = 0; t0 < T; t0 += SCAN_PF) {
            if (t0 && (t0 & (L_CHUNK - 1)) == 0) {
                int c = t0 >> 8;                       // L_CHUNK == 256
                emas[(size_t)c * N + ci] = ema;
                nrs[(size_t)c * N + ci] = nr;
                __threadfence();
                __syncthreads();
                if (threadIdx.x == 0)
                    __hip_atomic_fetch_add(&done[c], 1, __ATOMIC_RELEASE,
                                           __HIP_MEMORY_SCOPE_AGENT);
            }
            bool more = (t0 + SCAN_PF) < T;
            if (more) {
#pragma unroll
                for (int j = 0; j < SCAN_PF; ++j)
                    nxt[j] = xp[(size_t)(t0 + SCAN_PF + j) * F];
            }
            if (fast) {
#pragma unroll
                for (int j = 0; j < SCAN_PF; ++j) {
                    float xv = cur[j];
                    float d1 = xv - ema;
                    float am = alpha * d1;
                    ema = ema + am;
                    float d2 = xv - ema;
                    bool cross = fabsf(d2) >= thf;
                    int t = t0 + j;
                    bool tge = t >= nr;
                    bool fired = cross && tge;
                    nr = fired ? (t + 1 + rs) : nr;
                }
            } else {
#pragma unroll
                for (int j = 0; j < SCAN_PF; ++j) {
                    float xt = cur[j] * gf;
                    float d1 = xt - ema;
                    float am = alpha * d1;
                    ema = ema + am;
                    float d2 = xt - ema;
                    float av = Af * d2;
                    float vc = vbf - av;
                    float dv = vc - vbf;
                    bool cross = fabsf(dv) >= thf;
                    int t = t0 + j;
                    bool tge = t >= nr;
                    bool fired = cross && tge;
                    nr = fired ? (t + 1 + rs) : nr;
                }
            }
            if (more) {
#pragma unroll
                for (int j = 0; j < SCAN_PF; ++j) cur[j] = nxt[j];
            }
        }
    } else {
        // ---------------- emit role ----------------
        const int etid = ((int)blockIdx.x - nscan) * 256 + threadIdx.x;
        if (etid >= N * nchunks) return;
        const int k = etid / N;
        const int i = etid - k * N;
        const int f = i % F;
        const int b = i / F;
        const float vbf = vb[f], Af = A[f], thf = th[f], gf = gain[f];
        const int rs = (int)fmaxf(ceilf(tref[f] / 0.05f), 1.0f);

        const float* xp = x + (size_t)b * T * F + f;
        float* va_out   = out + (size_t)b * (T + 1) * F + f;
        float* sp_out   = out + (size_t)B * (T + 1) * F + (size_t)b * (T + 1) * F + f;

        const int tbeg = k * L_CHUNK;
        int tend = tbeg + L_CHUNK;
        if (tend > T) tend = T;

        float cur[K2_UNROLL], nxt[K2_UNROLL];
#pragma unroll
        for (int u = 0; u < K2_UNROLL; ++u) cur[u] = xp[(size_t)(tbeg + u) * F];

        float ema;
        int nr;
        if (k == 0) {
            ema = cur[0] * gf;       // t==0 seeding trick (see scan)
            nr = 0;
            va_out[0] = vbf;         // va_trace[:,0,:] = vb
        } else {
            // wait until all scan blocks have published chunk k's seeds
            while (__hip_atomic_load(&done[k], __ATOMIC_ACQUIRE,
                                     __HIP_MEMORY_SCOPE_AGENT) < nscan)
                __builtin_amdgcn_s_sleep(16);
            ema = emas[(size_t)k * N + i];
            nr = nrs[(size_t)k * N + i];
        }

        float last_sp = 0.0f;
        for (int t0 = tbeg; t0 < tend; t0 += K2_UNROLL) {
            if (t0 + K2_UNROLL < tend) {
#pragma unroll
                for (int u = 0; u < K2_UNROLL; ++u)
                    nxt[u] = xp[(size_t)(t0 + K2_UNROLL + u) * F];
            }
#pragma unroll
            for (int u = 0; u < K2_UNROLL; ++u) {
                int t = t0 + u;
                float xt = cur[u] * gf;
                float d1 = xt - ema;
                float am = alpha * d1;
                ema = ema + am;
                float d2 = xt - ema;
                float av = Af * d2;
                float vc = vbf - av;       // va_cand
                float dv = vc - vbf;
                bool cross = fabsf(dv) >= thf;
                bool tge = t >= nr;
                bool fired = cross && tge;
                float va_next = (cross || !tge) ? vbf : vc;
                nr = fired ? (t + 1 + rs) : nr;
                float spv = fired ? 1.0f : 0.0f;
                va_out[(size_t)(t + 1) * F] = va_next;
                sp_out[(size_t)t * F] = spv;
                last_sp = spv;
            }
#pragma unroll
            for (int u = 0; u < K2_UNROLL; ++u) cur[u] = nxt[u];
        }
        if (tend == T) sp_out[(size_t)T * F] = last_sp;   // spikes[:,T,:] = fired_{T-1}
    }
}

// Fallback: monolithic (used only if ws too small / shape odd).
__global__ __launch_bounds__(64, 1)
void fa_neuron_mono(const float* __restrict__ x,
                    const float* __restrict__ vb,
                    const float* __restrict__ A,
                    const float* __restrict__ th,
                    const float* __restrict__ gain,
                    const float* __restrict__ tref,
                    float* __restrict__ out,
                    int B, int T, int F) {
#pragma clang fp contract(off)
    int tid = blockIdx.x * blockDim.x + threadIdx.x;
    if (tid >= B * F) return;
    int f = tid % F;
    int b = tid / F;
    const float vbf = vb[f], Af = A[f], thf = th[f], gf = gain[f];
    const float alpha = 0.001f;
    int rs = (int)fmaxf(ceilf(tref[f] / 0.05f), 1.0f);
    const float* xp = x + (size_t)b * T * F + f;
    float* va_out   = out + (size_t)b * (T + 1) * F + f;
    float* sp_out   = out + (size_t)B * (T + 1) * F + (size_t)b * (T + 1) * F + f;
    va_out[0] = vbf;
    float ema = 0.0f;
    int nr = 0;
    for (int t = 0; t < T; ++t) {
        float xt = xp[(size_t)t * F] * gf;
        if (t == 0) {
            ema = xt;
        } else {
            float d1 = xt - ema;
            float am = alpha * d1;
            ema = ema + am;
        }
        float d2 = xt - ema;
        float av = Af * d2;
        float vc = vbf - av;
        float dv = vc - vbf;
        bool cross = fabsf(dv) >= thf;
        bool tge = t >= nr;
        bool fired = cross && tge;
        float va_next = (cross || !tge) ? vbf : vc;
        nr = fired ? (t + 1 + rs) : nr;
        float spv = fired ? 1.0f : 0.0f;
        va_out[(size_t)(t + 1) * F] = va_next;
        sp_out[(size_t)t * F] = spv;
        if (t == T - 1) sp_out[(size_t)T * F] = spv;
    }
}

extern "C" void kernel_launch(void* const* d_in, const int* in_sizes, int n_in,
                              void* d_out, int out_size, void* d_ws, size_t ws_size,
                              hipStream_t stream) {
    const float* x    = (const float*)d_in[0];
    const float* vb   = (const float*)d_in[1];
    const float* A    = (const float*)d_in[2];
    const float* th   = (const float*)d_in[3];
    const float* gain = (const float*)d_in[4];
    const float* tref = (const float*)d_in[5];
    float* out = (float*)d_out;

    int F = in_sizes[1];                                   // 512
    long long BF = (long long)out_size / 2 - in_sizes[0];  // B*F
    int B = (int)(BF / F);                                 // 16
    int T = (int)(in_sizes[0] / BF);                       // 4096
    int N = B * F;

    int nchunks = (T + L_CHUNK - 1) / L_CHUNK;
    size_t ws_need = (size_t)nchunks * N * (sizeof(float) + sizeof(int))
                   + (size_t)nchunks * sizeof(int);

    bool fused_ok = (ws_size >= ws_need) && (T % L_CHUNK == 0) &&
                    (T % SCAN_PF == 0) && (N % 256 == 0) &&
                    ((N * nchunks) % 256 == 0) && (L_CHUNK % K2_UNROLL == 0);

    if (!fused_ok) {
        int block = 64;
        int grid = (N + block - 1) / block;
        fa_neuron_mono<<<grid, block, 0, stream>>>(x, vb, A, th, gain, tref, out, B, T, F);
        return;
    }

    float* emas = (float*)d_ws;
    int*   nrs  = (int*)(emas + (size_t)nchunks * N);
    int*   done = (int*)(nrs + (size_t)nchunks * N);

    // reset chunk-ready flags (deterministic per launch; async on stream)
    hipMemsetAsync(done, 0, (size_t)nchunks * sizeof(int), stream);

    int nscan = N / 256;                         // 32 scan blocks
    int nemit = (N * nchunks) / 256;             // 512 emit blocks
    int grid = nscan + nemit;                    // 544 blocks, all co-resident
    fa_fused_kernel<<<grid, 256, 0, stream>>>(x, vb, A, th, gain, tref,
                                              emas, nrs, done, out,
                                              B, T, F, nchunks, nscan);
}

// Round 9
// 407.658 us; speedup vs baseline: 6.8280x; 6.8280x over previous
//
#include <hip/hip_runtime.h>
#include <stdint.h>

// FANeuron fused single-kernel producer/consumer (storm-proof sync):
//  - scan role (blockIdx < nscan): 1 chain/thread, 16-deep register prefetch,
//    sequential bit-exact recurrence; at every L_CHUNK boundary stores the
//    exact (ema, nr) seed and releases a per-chunk flag (agent scope).
//  - emit role: one thread per (chain, chunk). ONE thread per block polls the
//    chunk flag with RELAXED loads + s_sleep backoff (no acquire-invalidate
//    storm); the block then crosses one __threadfence() and replays its chunk
//    bit-exactly, writing va_trace + spikes.
//  All blocks co-resident (544 blocks x 4 waves, 0 LDS, VGPR<=64), so the
//  spin cannot deadlock. Emit keeps the chip busy while the serial scan runs.

#define L_CHUNK 256
#define SCAN_PF 16
#define K2_UNROLL 8

__global__ __launch_bounds__(256, 4)
void fa_fused_kernel(const float* __restrict__ x,
                     const float* __restrict__ vb,
                     const float* __restrict__ A,
                     const float* __restrict__ th,
                     const float* __restrict__ gain,
                     const float* __restrict__ tref,
                     float* __restrict__ emas,   // [nchunks][N]
                     int*   __restrict__ nrs,    // [nchunks][N]
                     int*   __restrict__ done,   // [nchunks]
                     float* __restrict__ out,
                     int B, int T, int F, int nchunks, int nscan) {
#pragma clang fp contract(off)
    const int N = B * F;
    const float alpha = 0.001f;                  // f32(0.05/50)

    if ((int)blockIdx.x < nscan) {
        // ---------------- scan role ----------------
        const int ci = blockIdx.x * 256 + threadIdx.x;   // = b*F + f
        const int f = ci % F;
        const int b = ci / F;
        const float vbf = vb[f], Af = A[f], thf = th[f], gf = gain[f];
        const int rs = (int)fmaxf(ceilf(tref[f] / 0.05f), 1.0f);
        const float* xp = x + (size_t)b * T * F + f;

        bool fast = __all((gf == 1.0f) && (Af == 1.0f) && (vbf == 0.0f));

        float cur[SCAN_PF], nxt[SCAN_PF];
#pragma unroll
        for (int j = 0; j < SCAN_PF; ++j) cur[j] = xp[(size_t)j * F];

        // bit-exact t==0 seeding: ema = xt(0); step t=0 then yields
        // fl(xt + alpha*0) = xt, so the loop needs no special case.
        float ema = fast ? cur[0] : (cur[0] * gf);
        int nr = 0;                                    // absolute next-ready step

        for (int t0 = 0; t0 < T; t0 += SCAN_PF) {
            if (t0 && (t0 & (L_CHUNK - 1)) == 0) {
                int c = t0 >> 8;                       // L_CHUNK == 256
                emas[(size_t)c * N + ci] = ema;
                nrs[(size_t)c * N + ci] = nr;
                __threadfence();
                __syncthreads();
                if (threadIdx.x == 0)
                    __hip_atomic_fetch_add(&done[c], 1, __ATOMIC_RELEASE,
                                           __HIP_MEMORY_SCOPE_AGENT);
            }
            bool more = (t0 + SCAN_PF) < T;
            if (more) {
#pragma unroll
                for (int j = 0; j < SCAN_PF; ++j)
                    nxt[j] = xp[(size_t)(t0 + SCAN_PF + j) * F];
            }
            if (fast) {
#pragma unroll
                for (int j = 0; j < SCAN_PF; ++j) {
                    float xv = cur[j];
                    float d1 = xv - ema;
                    float am = alpha * d1;
                    ema = ema + am;
                    float d2 = xv - ema;
                    bool cross = fabsf(d2) >= thf;
                    int t = t0 + j;
                    bool tge = t >= nr;
                    bool fired = cross && tge;
                    nr = fired ? (t + 1 + rs) : nr;
                }
            } else {
#pragma unroll
                for (int j = 0; j < SCAN_PF; ++j) {
                    float xt = cur[j] * gf;
                    float d1 = xt - ema;
                    float am = alpha * d1;
                    ema = ema + am;
                    float d2 = xt - ema;
                    float av = Af * d2;
                    float vc = vbf - av;
                    float dv = vc - vbf;
                    bool cross = fabsf(dv) >= thf;
                    int t = t0 + j;
                    bool tge = t >= nr;
                    bool fired = cross && tge;
                    nr = fired ? (t + 1 + rs) : nr;
                }
            }
            if (more) {
#pragma unroll
                for (int j = 0; j < SCAN_PF; ++j) cur[j] = nxt[j];
            }
        }
    } else {
        // ---------------- emit role ----------------
        const int etid = ((int)blockIdx.x - nscan) * 256 + threadIdx.x;
        if (etid >= N * nchunks) return;
        const int k = etid / N;             // constant within a block (N%256==0)
        const int i = etid - k * N;
        const int f = i % F;
        const int b = i / F;
        const float vbf = vb[f], Af = A[f], thf = th[f], gf = gain[f];
        const int rs = (int)fmaxf(ceilf(tref[f] / 0.05f), 1.0f);

        const float* xp = x + (size_t)b * T * F + f;
        float* va_out   = out + (size_t)b * (T + 1) * F + f;
        float* sp_out   = out + (size_t)B * (T + 1) * F + (size_t)b * (T + 1) * F + f;

        const int tbeg = k * L_CHUNK;
        int tend = tbeg + L_CHUNK;
        if (tend > T) tend = T;

        float cur[K2_UNROLL], nxt[K2_UNROLL];
#pragma unroll
        for (int u = 0; u < K2_UNROLL; ++u) cur[u] = xp[(size_t)(tbeg + u) * F];

        float ema;
        int nr;
        if (k == 0) {
            ema = cur[0] * gf;       // t==0 seeding trick (see scan)
            nr = 0;
            va_out[0] = vbf;         // va_trace[:,0,:] = vb
        } else {
            // ONE poller per block, relaxed loads + sleep backoff
            if (threadIdx.x == 0) {
                while (__hip_atomic_load(&done[k], __ATOMIC_RELAXED,
                                         __HIP_MEMORY_SCOPE_AGENT) < nscan)
                    __builtin_amdgcn_s_sleep(32);
            }
            __syncthreads();
            __threadfence();         // one acquire-strength fence for the block
            ema = emas[(size_t)k * N + i];
            nr = nrs[(size_t)k * N + i];
        }

        float last_sp = 0.0f;
        for (int t0 = tbeg; t0 < tend; t0 += K2_UNROLL) {
            if (t0 + K2_UNROLL < tend) {
#pragma unroll
                for (int u = 0; u < K2_UNROLL; ++u)
                    nxt[u] = xp[(size_t)(t0 + K2_UNROLL + u) * F];
            }
#pragma unroll
            for (int u = 0; u < K2_UNROLL; ++u) {
                int t = t0 + u;
                float xt = cur[u] * gf;
                float d1 = xt - ema;
                float am = alpha * d1;
                ema = ema + am;
                float d2 = xt - ema;
                float av = Af * d2;
                float vc = vbf - av;       // va_cand
                float dv = vc - vbf;
                bool cross = fabsf(dv) >= thf;
                bool tge = t >= nr;
                bool fired = cross && tge;
                float va_next = (cross || !tge) ? vbf : vc;
                nr = fired ? (t + 1 + rs) : nr;
                float spv = fired ? 1.0f : 0.0f;
                va_out[(size_t)(t + 1) * F] = va_next;
                sp_out[(size_t)t * F] = spv;
                last_sp = spv;
            }
#pragma unroll
            for (int u = 0; u < K2_UNROLL; ++u) cur[u] = nxt[u];
        }
        if (tend == T) sp_out[(size_t)T * F] = last_sp;   // spikes[:,T,:] = fired_{T-1}
    }
}

// Fallback: monolithic (used only if ws too small / shape odd).
__global__ __launch_bounds__(64, 1)
void fa_neuron_mono(const float* __restrict__ x,
                    const float* __restrict__ vb,
                    const float* __restrict__ A,
                    const float* __restrict__ th,
                    const float* __restrict__ gain,
                    const float* __restrict__ tref,
                    float* __restrict__ out,
                    int B, int T, int F) {
#pragma clang fp contract(off)
    int tid = blockIdx.x * blockDim.x + threadIdx.x;
    if (tid >= B * F) return;
    int f = tid % F;
    int b = tid / F;
    const float vbf = vb[f], Af = A[f], thf = th[f], gf = gain[f];
    const float alpha = 0.001f;
    int rs = (int)fmaxf(ceilf(tref[f] / 0.05f), 1.0f);
    const float* xp = x + (size_t)b * T * F + f;
    float* va_out   = out + (size_t)b * (T + 1) * F + f;
    float* sp_out   = out + (size_t)B * (T + 1) * F + (size_t)b * (T + 1) * F + f;
    va_out[0] = vbf;
    float ema = 0.0f;
    int nr = 0;
    for (int t = 0; t < T; ++t) {
        float xt = xp[(size_t)t * F] * gf;
        if (t == 0) {
            ema = xt;
        } else {
            float d1 = xt - ema;
            float am = alpha * d1;
            ema = ema + am;
        }
        float d2 = xt - ema;
        float av = Af * d2;
        float vc = vbf - av;
        float dv = vc - vbf;
        bool cross = fabsf(dv) >= thf;
        bool tge = t >= nr;
        bool fired = cross && tge;
        float va_next = (cross || !tge) ? vbf : vc;
        nr = fired ? (t + 1 + rs) : nr;
        float spv = fired ? 1.0f : 0.0f;
        va_out[(size_t)(t + 1) * F] = va_next;
        sp_out[(size_t)t * F] = spv;
        if (t == T - 1) sp_out[(size_t)T * F] = spv;
    }
}

extern "C" void kernel_launch(void* const* d_in, const int* in_sizes, int n_in,
                              void* d_out, int out_size, void* d_ws, size_t ws_size,
                              hipStream_t stream) {
    const float* x    = (const float*)d_in[0];
    const float* vb   = (const float*)d_in[1];
    const float* A    = (const float*)d_in[2];
    const float* th   = (const float*)d_in[3];
    const float* gain = (const float*)d_in[4];
    const float* tref = (const float*)d_in[5];
    float* out = (float*)d_out;

    int F = in_sizes[1];                                   // 512
    long long BF = (long long)out_size / 2 - in_sizes[0];  // B*F
    int B = (int)(BF / F);                                 // 16
    int T = (int)(in_sizes[0] / BF);                       // 4096
    int N = B * F;

    int nchunks = (T + L_CHUNK - 1) / L_CHUNK;
    size_t ws_need = (size_t)nchunks * N * (sizeof(float) + sizeof(int))
                   + (size_t)nchunks * sizeof(int);

    bool fused_ok = (ws_size >= ws_need) && (T % L_CHUNK == 0) &&
                    (T % SCAN_PF == 0) && (N % 256 == 0) &&
                    ((N * nchunks) % 256 == 0) && (L_CHUNK % K2_UNROLL == 0);

    if (!fused_ok) {
        int block = 64;
        int grid = (N + block - 1) / block;
        fa_neuron_mono<<<grid, block, 0, stream>>>(x, vb, A, th, gain, tref, out, B, T, F);
        return;
    }

    float* emas = (float*)d_ws;
    int*   nrs  = (int*)(emas + (size_t)nchunks * N);
    int*   done = (int*)(nrs + (size_t)nchunks * N);

    // reset chunk-ready flags (deterministic per launch; async on stream)
    hipMemsetAsync(done, 0, (size_t)nchunks * sizeof(int), stream);

    int nscan = N / 256;                         // 32 scan blocks
    int nemit = (N * nchunks) / 256;             // 512 emit blocks (chunk-major)
    int grid = nscan + nemit;                    // 544 blocks, all co-resident
    fa_fused_kernel<<<grid, 256, 0, stream>>>(x, vb, A, th, gain, tref,
                                              emas, nrs, done, out,
                                              B, T, F, nchunks, nscan);
}

// Round 10
// 158.765 us; speedup vs baseline: 17.5321x; 2.5677x over previous
//
#include <hip/hip_runtime.h>
#include <stdint.h>

// FANeuron two-pass:
//  K1 (scan): sequential per-chain recurrence, compute-only. 64-thread block
//             = 64 chains (one b, 64 features). Depth-4 global_load_lds ring,
//             counted s_waitcnt vmcnt(32). Inner loop: per-step work is ONLY
//             ema update + threshold-cross bit append (window bitmap);
//             refractory resolved once per 32-step window (valid when
//             rs>=31: at most one fire per window). ~7.5 issue slots/step.
//  K2 (emit): one thread per (chain, chunk) replays its chunk bit-exactly
//             from the seeded (ema, nr) state and writes va_trace + spikes.

#define L_CHUNK 256
#define TS 64          // timesteps per K1 tile
#define DEPTH 4        // LDS ring slots
#define K2_UNROLL 8

typedef const __attribute__((address_space(1))) uint32_t* gptr_t;
typedef __attribute__((address_space(3))) uint32_t* lptr_t;

__global__ __launch_bounds__(64, 1)
void fa_scan_kernel(const float* __restrict__ x,
                    const float* __restrict__ vb,
                    const float* __restrict__ A,
                    const float* __restrict__ th,
                    const float* __restrict__ gain,
                    const float* __restrict__ tref,
                    float* __restrict__ emas,   // [nchunks][N] (c>=1 used)
                    int*   __restrict__ nrs,    // [nchunks][N] (c>=1 used)
                    int B, int T, int F) {
#pragma clang fp contract(off)
    __shared__ float lds[DEPTH][TS][64];
    const int lane = threadIdx.x;
    const int gpb = F >> 6;
    const int bi = blockIdx.x;
    const int b = bi / gpb;
    const int f0 = (bi - b * gpb) << 6;
    const int f = f0 + lane;
    const int i = b * F + f;
    const int N = B * F;

    const float vbf = vb[f], Af = A[f], thf = th[f], gf = gain[f];
    const float alpha = 0.001f;                 // f32(0.05/50)
    const int rs = (int)fmaxf(ceilf(tref[f] / 0.05f), 1.0f);

    const float* xb = x + (size_t)b * T * F + f0;
    // per-lane DMA source: lane l covers row (l>>4), 16B at col (l&15)*4
    const float* gsrc0 = xb + (size_t)(lane >> 4) * F + ((lane & 15) << 2);
    const int ntiles = T / TS;

#define ISSUE_TILE(J)                                                         \
    do {                                                                      \
        const float* s_ = gsrc0 + (size_t)(J) * TS * F;                       \
        float* d_ = &lds[(J) & (DEPTH - 1)][0][0];                            \
        _Pragma("unroll")                                                     \
        for (int jj = 0; jj < 16; ++jj) {                                     \
            __builtin_amdgcn_global_load_lds(                                 \
                (gptr_t)(s_ + (size_t)(4 * jj) * F),                          \
                (lptr_t)(d_ + 4 * jj * 64), 16, 0, 0);                        \
        }                                                                     \
    } while (0)

    ISSUE_TILE(0);
    ISSUE_TILE(1);
    ISSUE_TILE(2);

    // fast path additionally requires rs>=31 so each 32-step window holds
    // at most one fire (min fire gap = rs+1 >= 32) -> branch-free resolve.
    bool fastAll = __all((gf == 1.0f) && (Af == 1.0f) && (vbf == 0.0f) &&
                         (rs >= 31));

    float ema = 0.0f;
    int nr = 0;                                  // ABSOLUTE next-ready step
    const int rs1 = rs;                          // nr = base + ffs(keep) + rs

    for (int k = 0; k < ntiles; ++k) {
        if (k < ntiles - 2)       asm volatile("s_waitcnt vmcnt(32)" ::: "memory");
        else if (k == ntiles - 2) asm volatile("s_waitcnt vmcnt(16)" ::: "memory");
        else                      asm volatile("s_waitcnt vmcnt(0)"  ::: "memory");
        __builtin_amdgcn_sched_barrier(0);

        const int slot = k & (DEPTH - 1);
        const int tb = k * TS;                   // absolute tile base

        if (k == 0) {
            // bit-exact t==0 seeding: ema = xt(0); step t=0 then computes
            // fl(xt + alpha*0) = xt and d2 = 0 -> matches reference exactly.
            float x0 = lds[0][0][lane];
            ema = fastAll ? x0 : (x0 * gf);
        } else if ((k & 3) == 0) {               // L_CHUNK/TS == 4
            int c = k >> 2;
            emas[(size_t)c * N + i] = ema;
            nrs[(size_t)c * N + i] = nr;
        }

        float ra[8], rb[8];
#pragma unroll
        for (int j = 0; j < 8; ++j) ra[j] = lds[slot][j][lane];

        if (fastAll) {
            uint32_t bits = 0;
#pragma unroll
            for (int t8 = 0; t8 < TS / 8; ++t8) {
                if (t8 < TS / 8 - 1) {
#pragma unroll
                    for (int j = 0; j < 8; ++j)
                        rb[j] = lds[slot][(t8 + 1) * 8 + j][lane];
                }
#pragma unroll
                for (int j = 0; j < 8; ++j) {
                    float xv = ra[j];
                    float d1 = xv - ema;
                    float am = alpha * d1;
                    ema = ema + am;
                    float d2 = xv - ema;
                    bool cross = fabsf(d2) >= thf;
                    bits = (bits << 1) | (cross ? 1u : 0u);
                }
                if (t8 == 3 || t8 == 7) {
                    // resolve one 32-step window (steps base .. base+31)
                    const int base = tb + ((t8 == 3) ? 0 : 32);
                    uint32_t rv = __brev(bits);  // bit j = cross at base+j
                    int rel = nr - base;
                    uint32_t keep;
                    if (rel <= 0)       keep = rv;
                    else if (rel >= 32) keep = 0u;
                    else                keep = rv & (0xFFFFFFFFu << rel);
                    int j1 = __ffs(keep);        // 1+index of first fire
                    nr = keep ? (base + j1 + rs1) : nr;  // t+1+rs
                    bits = 0;
                }
#pragma unroll
                for (int j = 0; j < 8; ++j) ra[j] = rb[j];
            }
        } else {
#pragma unroll
            for (int t8 = 0; t8 < TS / 8; ++t8) {
                if (t8 < TS / 8 - 1) {
#pragma unroll
                    for (int j = 0; j < 8; ++j)
                        rb[j] = lds[slot][(t8 + 1) * 8 + j][lane];
                }
#pragma unroll
                for (int j = 0; j < 8; ++j) {
                    const int t = tb + t8 * 8 + j;   // absolute step
                    float xt = ra[j] * gf;
                    float d1 = xt - ema;
                    float am = alpha * d1;
                    ema = ema + am;
                    float d2 = xt - ema;
                    float av = Af * d2;
                    float vc = vbf - av;
                    float dv = vc - vbf;
                    bool cross = fabsf(dv) >= thf;
                    bool tge = t >= nr;
                    bool fired = cross && tge;
                    nr = fired ? (t + 1 + rs) : nr;
                }
#pragma unroll
                for (int j = 0; j < 8; ++j) ra[j] = rb[j];
            }
        }

        if (k + 3 < ntiles) ISSUE_TILE(k + 3);
    }
#undef ISSUE_TILE
}

__global__ __launch_bounds__(256)
void fa_emit_kernel(const float* __restrict__ x,
                    const float* __restrict__ vb,
                    const float* __restrict__ A,
                    const float* __restrict__ th,
                    const float* __restrict__ gain,
                    const float* __restrict__ tref,
                    const float* __restrict__ emas,
                    const int*   __restrict__ nrs,
                    float* __restrict__ out,
                    int B, int T, int F, int nchunks) {
#pragma clang fp contract(off)
    int N = B * F;
    int tid = blockIdx.x * blockDim.x + threadIdx.x;
    if (tid >= N * nchunks) return;
    int i = tid % N;
    int k = tid / N;
    int f = i % F;
    int b = i / F;
    const float vbf = vb[f], Af = A[f], thf = th[f], gf = gain[f];
    const float alpha = 0.001f;
    int rs = (int)fmaxf(ceilf(tref[f] / 0.05f), 1.0f);

    const float* xp = x + (size_t)b * T * F + f;
    float* va_out   = out + (size_t)b * (T + 1) * F + f;
    float* sp_out   = out + (size_t)B * (T + 1) * F + (size_t)b * (T + 1) * F + f;

    int tbeg = k * L_CHUNK;
    int tend = tbeg + L_CHUNK;
    if (tend > T) tend = T;

    float cur[K2_UNROLL], nxt[K2_UNROLL];
#pragma unroll
    for (int u = 0; u < K2_UNROLL; ++u) cur[u] = xp[(size_t)(tbeg + u) * F];

    float ema;
    int nr;
    if (k == 0) {
        ema = cur[0] * gf;     // t==0 seeding trick (see K1)
        nr = 0;
        va_out[0] = vbf;       // va_trace[:,0,:] = vb
    } else {
        ema = emas[(size_t)k * N + i];
        nr = nrs[(size_t)k * N + i];
    }

    float last_sp = 0.0f;
    for (int t0 = tbeg; t0 < tend; t0 += K2_UNROLL) {
        if (t0 + K2_UNROLL < tend) {
#pragma unroll
            for (int u = 0; u < K2_UNROLL; ++u)
                nxt[u] = xp[(size_t)(t0 + K2_UNROLL + u) * F];
        }
#pragma unroll
        for (int u = 0; u < K2_UNROLL; ++u) {
            int t = t0 + u;
            float xt = cur[u] * gf;
            float d1 = xt - ema;
            float am = alpha * d1;
            ema = ema + am;
            float d2 = xt - ema;
            float av = Af * d2;
            float vc = vbf - av;       // va_cand
            float dv = vc - vbf;
            bool cross = fabsf(dv) >= thf;
            bool tge = t >= nr;
            bool fired = cross && tge;
            float va_next = (cross || !tge) ? vbf : vc;
            nr = fired ? (t + 1 + rs) : nr;
            float spv = fired ? 1.0f : 0.0f;
            va_out[(size_t)(t + 1) * F] = va_next;
            sp_out[(size_t)t * F] = spv;
            last_sp = spv;
        }
#pragma unroll
        for (int u = 0; u < K2_UNROLL; ++u) cur[u] = nxt[u];
    }
    if (tend == T) sp_out[(size_t)T * F] = last_sp;   // spikes[:,T,:] = fired_{T-1}
}

// Fallback: monolithic (used only if ws too small / shape odd).
__global__ __launch_bounds__(64, 1)
void fa_neuron_mono(const float* __restrict__ x,
                    const float* __restrict__ vb,
                    const float* __restrict__ A,
                    const float* __restrict__ th,
                    const float* __restrict__ gain,
                    const float* __restrict__ tref,
                    float* __restrict__ out,
                    int B, int T, int F) {
#pragma clang fp contract(off)
    int tid = blockIdx.x * blockDim.x + threadIdx.x;
    if (tid >= B * F) return;
    int f = tid % F;
    int b = tid / F;
    const float vbf = vb[f], Af = A[f], thf = th[f], gf = gain[f];
    const float alpha = 0.001f;
    int rs = (int)fmaxf(ceilf(tref[f] / 0.05f), 1.0f);
    const float* xp = x + (size_t)b * T * F + f;
    float* va_out   = out + (size_t)b * (T + 1) * F + f;
    float* sp_out   = out + (size_t)B * (T + 1) * F + (size_t)b * (T + 1) * F + f;
    va_out[0] = vbf;
    float ema = 0.0f;
    int nr = 0;
    for (int t = 0; t < T; ++t) {
        float xt = xp[(size_t)t * F] * gf;
        if (t == 0) {
            ema = xt;
        } else {
            float d1 = xt - ema;
            float am = alpha * d1;
            ema = ema + am;
        }
        float d2 = xt - ema;
        float av = Af * d2;
        float vc = vbf - av;
        float dv = vc - vbf;
        bool cross = fabsf(dv) >= thf;
        bool tge = t >= nr;
        bool fired = cross && tge;
        float va_next = (cross || !tge) ? vbf : vc;
        nr = fired ? (t + 1 + rs) : nr;
        float spv = fired ? 1.0f : 0.0f;
        va_out[(size_t)(t + 1) * F] = va_next;
        sp_out[(size_t)t * F] = spv;
        if (t == T - 1) sp_out[(size_t)T * F] = spv;
    }
}

extern "C" void kernel_launch(void* const* d_in, const int* in_sizes, int n_in,
                              void* d_out, int out_size, void* d_ws, size_t ws_size,
                              hipStream_t stream) {
    const float* x    = (const float*)d_in[0];
    const float* vb   = (const float*)d_in[1];
    const float* A    = (const float*)d_in[2];
    const float* th   = (const float*)d_in[3];
    const float* gain = (const float*)d_in[4];
    const float* tref = (const float*)d_in[5];
    float* out = (float*)d_out;

    int F = in_sizes[1];                                   // 512
    long long BF = (long long)out_size / 2 - in_sizes[0];  // B*F
    int B = (int)(BF / F);                                 // 16
    int T = (int)(in_sizes[0] / BF);                       // 4096
    int N = B * F;

    int nchunks = (T + L_CHUNK - 1) / L_CHUNK;
    size_t ws_need = (size_t)nchunks * N * (sizeof(float) + sizeof(int));

    bool tiled_ok = (ws_size >= ws_need) && (T % L_CHUNK == 0) &&
                    (T % TS == 0) && (T / TS >= 4) && (F % 64 == 0) &&
                    (L_CHUNK == 4 * TS);

    if (!tiled_ok) {
        int block = 64;
        int grid = (N + block - 1) / block;
        fa_neuron_mono<<<grid, block, 0, stream>>>(x, vb, A, th, gain, tref, out, B, T, F);
        return;
    }

    float* emas = (float*)d_ws;
    int*   nrs  = (int*)(emas + (size_t)nchunks * N);

    {
        int block = 64;
        int grid = N / 64;   // one 64-chain group per block
        fa_scan_kernel<<<grid, block, 0, stream>>>(x, vb, A, th, gain, tref,
                                                   emas, nrs, B, T, F);
    }
    {
        int total = N * nchunks;
        int block = 256;
        int grid = (total + block - 1) / block;
        fa_emit_kernel<<<grid, block, 0, stream>>>(x, vb, A, th, gain, tref,
                                                   emas, nrs, out, B, T, F, nchunks);
    }
}

// Round 11
// 149.280 us; speedup vs baseline: 18.6461x; 1.0635x over previous
//
#include <hip/hip_runtime.h>
#include <stdint.h>

// FANeuron two-pass:
//  K1 (scan): sequential per-chain recurrence, compute-only. 64-thread block
//             = 64 chains. Depth-4 global_load_lds ring, counted vmcnt(32).
//             FAST PATH: hand-scheduled inline-asm software pipeline,
//             6 instr/step, 12-cyc steady-state period:
//               [E-add, addc_{j-1}, d1_{j+1}, d2_j, am_{j+1}, cmp_j]
//             Refractory via 32-step window bitmap (valid: rs>=31).
//  K2 (emit): one thread per (chain, chunk) replays its chunk bit-exactly
//             from the seeded (ema, nr) state and writes va_trace + spikes.

#define L_CHUNK 256
#define TS 64          // timesteps per K1 tile
#define DEPTH 4        // LDS ring slots
#define K2_UNROLL 8

typedef const __attribute__((address_space(1))) uint32_t* gptr_t;
typedef __attribute__((address_space(3))) uint32_t* lptr_t;

// 8 bit-exact steps, hand-pipelined. ema/bits carried; vcc clobbered.
// Rounding identical to C: v_sub/v_mul/v_add f32 round-to-nearest-even.
#define FA_ASM8(A)                                                         \
    asm volatile(                                                          \
        /* prologue: d1_0, am_0, E_0 */                                    \
        "v_sub_f32 %[d1], %[a0], %[ema]\n\t"                               \
        "v_mul_f32 %[am], %[al], %[d1]\n\t"                                \
        "v_add_f32 %[ema], %[ema], %[am]\n\t"                              \
        /* period j=0 */                                                   \
        "v_sub_f32 %[d1], %[a1], %[ema]\n\t"                               \
        "v_sub_f32 %[d2], %[a0], %[ema]\n\t"                               \
        "v_mul_f32 %[am], %[al], %[d1]\n\t"                                \
        "v_cmp_le_f32_e64 vcc, %[th], |%[d2]|\n\t"                         \
        "v_add_f32 %[ema], %[ema], %[am]\n\t"                              \
        "v_addc_co_u32 %[bits], vcc, %[bits], %[bits], vcc\n\t"            \
        /* period j=1 */                                                   \
        "v_sub_f32 %[d1], %[a2], %[ema]\n\t"                               \
        "v_sub_f32 %[d2], %[a1], %[ema]\n\t"                               \
        "v_mul_f32 %[am], %[al], %[d1]\n\t"                                \
        "v_cmp_le_f32_e64 vcc, %[th], |%[d2]|\n\t"                         \
        "v_add_f32 %[ema], %[ema], %[am]\n\t"                              \
        "v_addc_co_u32 %[bits], vcc, %[bits], %[bits], vcc\n\t"            \
        /* period j=2 */                                                   \
        "v_sub_f32 %[d1], %[a3], %[ema]\n\t"                               \
        "v_sub_f32 %[d2], %[a2], %[ema]\n\t"                               \
        "v_mul_f32 %[am], %[al], %[d1]\n\t"                                \
        "v_cmp_le_f32_e64 vcc, %[th], |%[d2]|\n\t"                         \
        "v_add_f32 %[ema], %[ema], %[am]\n\t"                              \
        "v_addc_co_u32 %[bits], vcc, %[bits], %[bits], vcc\n\t"            \
        /* period j=3 */                                                   \
        "v_sub_f32 %[d1], %[a4], %[ema]\n\t"                               \
        "v_sub_f32 %[d2], %[a3], %[ema]\n\t"                               \
        "v_mul_f32 %[am], %[al], %[d1]\n\t"                                \
        "v_cmp_le_f32_e64 vcc, %[th], |%[d2]|\n\t"                         \
        "v_add_f32 %[ema], %[ema], %[am]\n\t"                              \
        "v_addc_co_u32 %[bits], vcc, %[bits], %[bits], vcc\n\t"            \
        /* period j=4 */                                                   \
        "v_sub_f32 %[d1], %[a5], %[ema]\n\t"                               \
        "v_sub_f32 %[d2], %[a4], %[ema]\n\t"                               \
        "v_mul_f32 %[am], %[al], %[d1]\n\t"                                \
        "v_cmp_le_f32_e64 vcc, %[th], |%[d2]|\n\t"                         \
        "v_add_f32 %[ema], %[ema], %[am]\n\t"                              \
        "v_addc_co_u32 %[bits], vcc, %[bits], %[bits], vcc\n\t"            \
        /* period j=5 */                                                   \
        "v_sub_f32 %[d1], %[a6], %[ema]\n\t"                               \
        "v_sub_f32 %[d2], %[a5], %[ema]\n\t"                               \
        "v_mul_f32 %[am], %[al], %[d1]\n\t"                                \
        "v_cmp_le_f32_e64 vcc, %[th], |%[d2]|\n\t"                         \
        "v_add_f32 %[ema], %[ema], %[am]\n\t"                              \
        "v_addc_co_u32 %[bits], vcc, %[bits], %[bits], vcc\n\t"            \
        /* period j=6 */                                                   \
        "v_sub_f32 %[d1], %[a7], %[ema]\n\t"                               \
        "v_sub_f32 %[d2], %[a6], %[ema]\n\t"                               \
        "v_mul_f32 %[am], %[al], %[d1]\n\t"                                \
        "v_cmp_le_f32_e64 vcc, %[th], |%[d2]|\n\t"                         \
        "v_add_f32 %[ema], %[ema], %[am]\n\t"                              \
        "v_addc_co_u32 %[bits], vcc, %[bits], %[bits], vcc\n\t"            \
        /* epilogue: d2_7, cmp_7, addc_7 */                                \
        "v_sub_f32 %[d2], %[a7], %[ema]\n\t"                               \
        "v_cmp_le_f32_e64 vcc, %[th], |%[d2]|\n\t"                         \
        "v_addc_co_u32 %[bits], vcc, %[bits], %[bits], vcc"                \
        : [ema]"+v"(ema), [bits]"+v"(bits),                                \
          [d1]"=&v"(td1), [d2]"=&v"(td2), [am]"=&v"(tam)                   \
        : [a0]"v"((A)[0]), [a1]"v"((A)[1]), [a2]"v"((A)[2]),               \
          [a3]"v"((A)[3]), [a4]"v"((A)[4]), [a5]"v"((A)[5]),               \
          [a6]"v"((A)[6]), [a7]"v"((A)[7]),                                \
          [th]"v"(thf), [al]"s"(alpha)                                     \
        : "vcc")

#define FA_RESOLVE(BASE)                                                   \
    do {                                                                   \
        uint32_t rv = __brev(bits);   /* bit j = cross at (BASE)+j */      \
        int rel = nr - (BASE);                                             \
        uint32_t keep = (rel <= 0) ? rv                                    \
                      : ((rel >= 32) ? 0u : (rv & (0xFFFFFFFFu << rel)));  \
        int j1 = __ffs(keep);                                              \
        nr = keep ? ((BASE) + j1 + rs) : nr;   /* t+1+rs */                \
        bits = 0;                                                          \
    } while (0)

__global__ __launch_bounds__(64, 1)
void fa_scan_kernel(const float* __restrict__ x,
                    const float* __restrict__ vb,
                    const float* __restrict__ A,
                    const float* __restrict__ th,
                    const float* __restrict__ gain,
                    const float* __restrict__ tref,
                    float* __restrict__ emas,   // [nchunks][N] (c>=1 used)
                    int*   __restrict__ nrs,    // [nchunks][N] (c>=1 used)
                    int B, int T, int F) {
#pragma clang fp contract(off)
    __shared__ float lds[DEPTH][TS][64];
    const int lane = threadIdx.x;
    const int gpb = F >> 6;
    const int bi = blockIdx.x;
    const int b = bi / gpb;
    const int f0 = (bi - b * gpb) << 6;
    const int f = f0 + lane;
    const int i = b * F + f;
    const int N = B * F;

    const float vbf = vb[f], Af = A[f], thf = th[f], gf = gain[f];
    const float alpha = 0.001f;                 // f32(0.05/50)
    const int rs = (int)fmaxf(ceilf(tref[f] / 0.05f), 1.0f);

    const float* xb = x + (size_t)b * T * F + f0;
    const float* gsrc0 = xb + (size_t)(lane >> 4) * F + ((lane & 15) << 2);
    const int ntiles = T / TS;

#define ISSUE_TILE(J)                                                         \
    do {                                                                      \
        const float* s_ = gsrc0 + (size_t)(J) * TS * F;                       \
        float* d_ = &lds[(J) & (DEPTH - 1)][0][0];                            \
        _Pragma("unroll")                                                     \
        for (int jj = 0; jj < 16; ++jj) {                                     \
            __builtin_amdgcn_global_load_lds(                                 \
                (gptr_t)(s_ + (size_t)(4 * jj) * F),                          \
                (lptr_t)(d_ + 4 * jj * 64), 16, 0, 0);                        \
        }                                                                     \
    } while (0)

    ISSUE_TILE(0);
    ISSUE_TILE(1);
    ISSUE_TILE(2);

    // fast path requires rs>=31 (max one fire per 32-step window)
    bool fastAll = __all((gf == 1.0f) && (Af == 1.0f) && (vbf == 0.0f) &&
                         (rs >= 31));

    float ema = 0.0f;
    int nr = 0;                                  // ABSOLUTE next-ready step
    uint32_t bits = 0;
    float td1, td2, tam;

    for (int k = 0; k < ntiles; ++k) {
        if (k < ntiles - 2)       asm volatile("s_waitcnt vmcnt(32)" ::: "memory");
        else if (k == ntiles - 2) asm volatile("s_waitcnt vmcnt(16)" ::: "memory");
        else                      asm volatile("s_waitcnt vmcnt(0)"  ::: "memory");
        __builtin_amdgcn_sched_barrier(0);

        const int slot = k & (DEPTH - 1);
        const int tb = k * TS;

        if (k == 0) {
            // bit-exact t==0 seeding: ema = xt(0); step 0 then computes
            // d1=0, E_0=xt, d2=0 -> matches reference exactly.
            float x0 = lds[0][0][lane];
            ema = fastAll ? x0 : (x0 * gf);
        } else if ((k & 3) == 0) {               // L_CHUNK/TS == 4
            int c = k >> 2;
            emas[(size_t)c * N + i] = ema;
            nrs[(size_t)c * N + i] = nr;
        }

        if (fastAll) {
            float Ab[8], Bb[8];
#pragma unroll
            for (int j = 0; j < 8; ++j) Ab[j] = lds[slot][j][lane];        // batch 0
#pragma unroll
            for (int j = 0; j < 8; ++j) Bb[j] = lds[slot][8 + j][lane];    // batch 1
            FA_ASM8(Ab);                                                   // steps 0-7
#pragma unroll
            for (int j = 0; j < 8; ++j) Ab[j] = lds[slot][16 + j][lane];   // batch 2
            FA_ASM8(Bb);                                                   // 8-15
#pragma unroll
            for (int j = 0; j < 8; ++j) Bb[j] = lds[slot][24 + j][lane];   // batch 3
            FA_ASM8(Ab);                                                   // 16-23
#pragma unroll
            for (int j = 0; j < 8; ++j) Ab[j] = lds[slot][32 + j][lane];   // batch 4
            FA_ASM8(Bb);                                                   // 24-31
            FA_RESOLVE(tb);                                                // window 0
#pragma unroll
            for (int j = 0; j < 8; ++j) Bb[j] = lds[slot][40 + j][lane];   // batch 5
            FA_ASM8(Ab);                                                   // 32-39
#pragma unroll
            for (int j = 0; j < 8; ++j) Ab[j] = lds[slot][48 + j][lane];   // batch 6
            FA_ASM8(Bb);                                                   // 40-47
#pragma unroll
            for (int j = 0; j < 8; ++j) Bb[j] = lds[slot][56 + j][lane];   // batch 7
            FA_ASM8(Ab);                                                   // 48-55
            FA_ASM8(Bb);                                                   // 56-63
            FA_RESOLVE(tb + 32);                                           // window 1
        } else {
            float ra[8], rb[8];
#pragma unroll
            for (int j = 0; j < 8; ++j) ra[j] = lds[slot][j][lane];
#pragma unroll
            for (int t8 = 0; t8 < TS / 8; ++t8) {
                if (t8 < TS / 8 - 1) {
#pragma unroll
                    for (int j = 0; j < 8; ++j)
                        rb[j] = lds[slot][(t8 + 1) * 8 + j][lane];
                }
#pragma unroll
                for (int j = 0; j < 8; ++j) {
                    const int t = tb + t8 * 8 + j;
                    float xt = ra[j] * gf;
                    float d1 = xt - ema;
                    float am = alpha * d1;
                    ema = ema + am;
                    float d2 = xt - ema;
                    float av = Af * d2;
                    float vc = vbf - av;
                    float dv = vc - vbf;
                    bool cross = fabsf(dv) >= thf;
                    bool tge = t >= nr;
                    bool fired = cross && tge;
                    nr = fired ? (t + 1 + rs) : nr;
                }
#pragma unroll
                for (int j = 0; j < 8; ++j) ra[j] = rb[j];
            }
        }

        if (k + 3 < ntiles) ISSUE_TILE(k + 3);
    }
#undef ISSUE_TILE
}

__global__ __launch_bounds__(256)
void fa_emit_kernel(const float* __restrict__ x,
                    const float* __restrict__ vb,
                    const float* __restrict__ A,
                    const float* __restrict__ th,
                    const float* __restrict__ gain,
                    const float* __restrict__ tref,
                    const float* __restrict__ emas,
                    const int*   __restrict__ nrs,
                    float* __restrict__ out,
                    int B, int T, int F, int nchunks) {
#pragma clang fp contract(off)
    int N = B * F;
    int tid = blockIdx.x * blockDim.x + threadIdx.x;
    if (tid >= N * nchunks) return;
    int i = tid % N;
    int k = tid / N;
    int f = i % F;
    int b = i / F;
    const float vbf = vb[f], Af = A[f], thf = th[f], gf = gain[f];
    const float alpha = 0.001f;
    int rs = (int)fmaxf(ceilf(tref[f] / 0.05f), 1.0f);

    const float* xp = x + (size_t)b * T * F + f;
    float* va_out   = out + (size_t)b * (T + 1) * F + f;
    float* sp_out   = out + (size_t)B * (T + 1) * F + (size_t)b * (T + 1) * F + f;

    int tbeg = k * L_CHUNK;
    int tend = tbeg + L_CHUNK;
    if (tend > T) tend = T;

    float cur[K2_UNROLL], nxt[K2_UNROLL];
#pragma unroll
    for (int u = 0; u < K2_UNROLL; ++u) cur[u] = xp[(size_t)(tbeg + u) * F];

    float ema;
    int nr;
    if (k == 0) {
        ema = cur[0] * gf;     // t==0 seeding trick (see K1)
        nr = 0;
        va_out[0] = vbf;       // va_trace[:,0,:] = vb
    } else {
        ema = emas[(size_t)k * N + i];
        nr = nrs[(size_t)k * N + i];
    }

    float last_sp = 0.0f;
    for (int t0 = tbeg; t0 < tend; t0 += K2_UNROLL) {
        if (t0 + K2_UNROLL < tend) {
#pragma unroll
            for (int u = 0; u < K2_UNROLL; ++u)
                nxt[u] = xp[(size_t)(t0 + K2_UNROLL + u) * F];
        }
#pragma unroll
        for (int u = 0; u < K2_UNROLL; ++u) {
            int t = t0 + u;
            float xt = cur[u] * gf;
            float d1 = xt - ema;
            float am = alpha * d1;
            ema = ema + am;
            float d2 = xt - ema;
            float av = Af * d2;
            float vc = vbf - av;       // va_cand
            float dv = vc - vbf;
            bool cross = fabsf(dv) >= thf;
            bool tge = t >= nr;
            bool fired = cross && tge;
            float va_next = (cross || !tge) ? vbf : vc;
            nr = fired ? (t + 1 + rs) : nr;
            float spv = fired ? 1.0f : 0.0f;
            va_out[(size_t)(t + 1) * F] = va_next;
            sp_out[(size_t)t * F] = spv;
            last_sp = spv;
        }
#pragma unroll
        for (int u = 0; u < K2_UNROLL; ++u) cur[u] = nxt[u];
    }
    if (tend == T) sp_out[(size_t)T * F] = last_sp;   // spikes[:,T,:] = fired_{T-1}
}

// Fallback: monolithic (used only if ws too small / shape odd).
__global__ __launch_bounds__(64, 1)
void fa_neuron_mono(const float* __restrict__ x,
                    const float* __restrict__ vb,
                    const float* __restrict__ A,
                    const float* __restrict__ th,
                    const float* __restrict__ gain,
                    const float* __restrict__ tref,
                    float* __restrict__ out,
                    int B, int T, int F) {
#pragma clang fp contract(off)
    int tid = blockIdx.x * blockDim.x + threadIdx.x;
    if (tid >= B * F) return;
    int f = tid % F;
    int b = tid / F;
    const float vbf = vb[f], Af = A[f], thf = th[f], gf = gain[f];
    const float alpha = 0.001f;
    int rs = (int)fmaxf(ceilf(tref[f] / 0.05f), 1.0f);
    const float* xp = x + (size_t)b * T * F + f;
    float* va_out   = out + (size_t)b * (T + 1) * F + f;
    float* sp_out   = out + (size_t)B * (T + 1) * F + (size_t)b * (T + 1) * F + f;
    va_out[0] = vbf;
    float ema = 0.0f;
    int nr = 0;
    for (int t = 0; t < T; ++t) {
        float xt = xp[(size_t)t * F] * gf;
        if (t == 0) {
            ema = xt;
        } else {
            float d1 = xt - ema;
            float am = alpha * d1;
            ema = ema + am;
        }
        float d2 = xt - ema;
        float av = Af * d2;
        float vc = vbf - av;
        float dv = vc - vbf;
        bool cross = fabsf(dv) >= thf;
        bool tge = t >= nr;
        bool fired = cross && tge;
        float va_next = (cross || !tge) ? vbf : vc;
        nr = fired ? (t + 1 + rs) : nr;
        float spv = fired ? 1.0f : 0.0f;
        va_out[(size_t)(t + 1) * F] = va_next;
        sp_out[(size_t)t * F] = spv;
        if (t == T - 1) sp_out[(size_t)T * F] = spv;
    }
}

extern "C" void kernel_launch(void* const* d_in, const int* in_sizes, int n_in,
                              void* d_out, int out_size, void* d_ws, size_t ws_size,
                              hipStream_t stream) {
    const float* x    = (const float*)d_in[0];
    const float* vb   = (const float*)d_in[1];
    const float* A    = (const float*)d_in[2];
    const float* th   = (const float*)d_in[3];
    const float* gain = (const float*)d_in[4];
    const float* tref = (const float*)d_in[5];
    float* out = (float*)d_out;

    int F = in_sizes[1];                                   // 512
    long long BF = (long long)out_size / 2 - in_sizes[0];  // B*F
    int B = (int)(BF / F);                                 // 16
    int T = (int)(in_sizes[0] / BF);                       // 4096
    int N = B * F;

    int nchunks = (T + L_CHUNK - 1) / L_CHUNK;
    size_t ws_need = (size_t)nchunks * N * (sizeof(float) + sizeof(int));

    bool tiled_ok = (ws_size >= ws_need) && (T % L_CHUNK == 0) &&
                    (T % TS == 0) && (T / TS >= 4) && (F % 64 == 0) &&
                    (L_CHUNK == 4 * TS);

    if (!tiled_ok) {
        int block = 64;
        int grid = (N + block - 1) / block;
        fa_neuron_mono<<<grid, block, 0, stream>>>(x, vb, A, th, gain, tref, out, B, T, F);
        return;
    }

    float* emas = (float*)d_ws;
    int*   nrs  = (int*)(emas + (size_t)nchunks * N);

    {
        int block = 64;
        int grid = N / 64;   // one 64-chain group per block
        fa_scan_kernel<<<grid, block, 0, stream>>>(x, vb, A, th, gain, tref,
                                                   emas, nrs, B, T, F);
    }
    {
        int total = N * nchunks;
        int block = 256;
        int grid = (total + block - 1) / block;
        fa_emit_kernel<<<grid, block, 0, stream>>>(x, vb, A, th, gain, tref,
                                                   emas, nrs, out, B, T, F, nchunks);
    }
}